// Round 1
// baseline (2180.458 us; speedup 1.0000x reference)
//
#include <hip/hip_runtime.h>
#include <hip/hip_bf16.h>

#define N_NODES 50000
#define KNN     16
#define NEDGE   (N_NODES*KNN)   // 800000
#define C       64
#define CH      128             // 2*C_IN
#define EB      64              // edges per tile
#define NTILE   (NEDGE/EB)      // 12500
#define SLOPE   0.01f
#define EPS     1e-5f

__device__ __forceinline__ float bfbits(unsigned int u){
  union { unsigned int u; float f; } v; v.u = u; return v.f;
}
__device__ __forceinline__ unsigned short f2bf(float f){
  __hip_bfloat16 h = __float2bfloat16(f);
  union { __hip_bfloat16 h; unsigned short u; } v; v.h = h; return v.u;
}
__device__ __forceinline__ float lrelu(float v){ return v >= 0.f ? v : SLOPE*v; }

// ---------------- Kernel A: h = [x_i, x_j - x_i]; z1 = h@W1 + b1; stats1 ----
__global__ __launch_bounds__(256) void kA(const float* __restrict__ x,
    const int* __restrict__ ei, const float* __restrict__ W1,
    const float* __restrict__ b1, unsigned short* __restrict__ z,
    float* __restrict__ stats)
{
  __shared__ float hbuf[EB][CH+1];   // 64 x 129 f32 = 33 KB, conflict-free reads
  const int t = threadIdx.x;
  const int s = t & 63;                               // edge slot (lane)
  const int c0 = __builtin_amdgcn_readfirstlane(t >> 6) * 16;  // wave-uniform channel block

  float sumP[16], sqP[16];
#pragma unroll
  for (int j=0;j<16;++j){ sumP[j]=0.f; sqP[j]=0.f; }

  for (int tile = blockIdx.x; tile < NTILE; tile += gridDim.x) {
    const int e = tile*EB + s;
    {
      const int src = ei[e];
      const int dst = e >> 4;          // dst = repeat(arange(N),16)
      const float4* xi = (const float4*)(x + (size_t)dst*C + c0);
      const float4* xj = (const float4*)(x + (size_t)src*C + c0);
#pragma unroll
      for (int q=0;q<4;++q){
        float4 a = xi[q], b = xj[q];
        const int cc = c0 + q*4;
        hbuf[s][cc+0]=a.x; hbuf[s][cc+1]=a.y; hbuf[s][cc+2]=a.z; hbuf[s][cc+3]=a.w;
        hbuf[s][64+cc+0]=b.x-a.x; hbuf[s][64+cc+1]=b.y-a.y;
        hbuf[s][64+cc+2]=b.z-a.z; hbuf[s][64+cc+3]=b.w-a.w;
      }
    }
    __syncthreads();

    float acc[16];
#pragma unroll
    for (int j=0;j<16;++j) acc[j] = b1[c0+j];
#pragma unroll 8
    for (int k=0;k<CH;++k){
      const float hk = hbuf[s][k];
      const float* __restrict__ wp = W1 + (k<<6) + c0;   // wave-uniform -> s_load
#pragma unroll
      for (int j=0;j<16;++j) acc[j] = fmaf(hk, wp[j], acc[j]);
    }

#pragma unroll
    for (int j=0;j<16;++j){ sumP[j] += acc[j]; sqP[j] += acc[j]*acc[j]; }

    unsigned int pk[8];
#pragma unroll
    for (int q=0;q<8;++q)
      pk[q] = (unsigned int)f2bf(acc[2*q]) | ((unsigned int)f2bf(acc[2*q+1]) << 16);
    uint4* zp = (uint4*)(z + (size_t)e*C + c0);
    zp[0] = make_uint4(pk[0],pk[1],pk[2],pk[3]);
    zp[1] = make_uint4(pk[4],pk[5],pk[6],pk[7]);
    __syncthreads();
  }

#pragma unroll
  for (int j=0;j<16;++j){
    float v1 = sumP[j], v2 = sqP[j];
#pragma unroll
    for (int off=32; off>0; off>>=1){
      v1 += __shfl_xor(v1, off, 64);
      v2 += __shfl_xor(v2, off, 64);
    }
    if (s == 0){
      atomicAdd(&stats[c0+j], v1);
      atomicAdd(&stats[64+c0+j], v2);
    }
  }
}

// ------------- Finalize BN: a = g*rsqrt(var+eps), c = be - mean*a -----------
__global__ void kFin(const float* __restrict__ stats, const float* __restrict__ g,
                     const float* __restrict__ be, float* __restrict__ coefs, int which)
{
  const int c = threadIdx.x;   // 64 threads
  const float inv = 1.0f / (float)NEDGE;
  const float mean = stats[which*128 + c] * inv;
  const float var  = stats[which*128 + 64 + c] * inv - mean*mean;
  const float a = g[c] / sqrtf(var + EPS);
  coefs[which*128 + c]      = a;
  coefs[which*128 + 64 + c] = be[c] - mean * a;
}

// ---- Kernel B: h1 = lrelu(a1*z1+c1); z2 = h1@W2 + b2 (in-place); stats2 ----
__global__ __launch_bounds__(256) void kB(unsigned short* __restrict__ z,
    const float* __restrict__ W2, const float* __restrict__ b2,
    const float* __restrict__ coefs, float* __restrict__ stats)
{
  __shared__ float hbuf[EB][C+1];
  const int t = threadIdx.x;
  const int s = t & 63;
  const int c0 = __builtin_amdgcn_readfirstlane(t >> 6) * 16;

  float sumP[16], sqP[16];
#pragma unroll
  for (int j=0;j<16;++j){ sumP[j]=0.f; sqP[j]=0.f; }

  for (int tile = blockIdx.x; tile < NTILE; tile += gridDim.x) {
    const int e = tile*EB + s;
    {
      const uint4* zp = (const uint4*)(z + (size_t)e*C + c0);
      const uint4 v0 = zp[0], v1 = zp[1];
      const unsigned int u[8] = {v0.x,v0.y,v0.z,v0.w,v1.x,v1.y,v1.z,v1.w};
#pragma unroll
      for (int q=0;q<8;++q){
        const int cc = c0 + 2*q;
        const float f0 = bfbits(u[q] << 16);
        const float f1 = bfbits(u[q] & 0xffff0000u);
        hbuf[s][cc]   = lrelu(fmaf(coefs[cc],   f0, coefs[64+cc]));
        hbuf[s][cc+1] = lrelu(fmaf(coefs[cc+1], f1, coefs[64+cc+1]));
      }
    }
    __syncthreads();

    float acc[16];
#pragma unroll
    for (int j=0;j<16;++j) acc[j] = b2[c0+j];
#pragma unroll 8
    for (int k=0;k<C;++k){
      const float hk = hbuf[s][k];
      const float* __restrict__ wp = W2 + (k<<6) + c0;
#pragma unroll
      for (int j=0;j<16;++j) acc[j] = fmaf(hk, wp[j], acc[j]);
    }

#pragma unroll
    for (int j=0;j<16;++j){ sumP[j] += acc[j]; sqP[j] += acc[j]*acc[j]; }

    unsigned int pk[8];
#pragma unroll
    for (int q=0;q<8;++q)
      pk[q] = (unsigned int)f2bf(acc[2*q]) | ((unsigned int)f2bf(acc[2*q+1]) << 16);
    uint4* zp = (uint4*)(z + (size_t)e*C + c0);
    zp[0] = make_uint4(pk[0],pk[1],pk[2],pk[3]);
    zp[1] = make_uint4(pk[4],pk[5],pk[6],pk[7]);
    __syncthreads();
  }

#pragma unroll
  for (int j=0;j<16;++j){
    float v1 = sumP[j], v2 = sqP[j];
#pragma unroll
    for (int off=32; off>0; off>>=1){
      v1 += __shfl_xor(v1, off, 64);
      v2 += __shfl_xor(v2, off, 64);
    }
    if (s == 0){
      atomicAdd(&stats[128 + c0+j], v1);
      atomicAdd(&stats[192 + c0+j], v2);
    }
  }
}

// -- Kernel C: h2 = lrelu(a2*z2+c2); z3 = h2@W3+b3; segmax; lrelu(out+x) ----
__global__ __launch_bounds__(256) void kC(const unsigned short* __restrict__ z,
    const float* __restrict__ W3, const float* __restrict__ b3,
    const float* __restrict__ coefs2, const float* __restrict__ x,
    float* __restrict__ out)
{
  __shared__ float hbuf[EB][C+1];
  const int t = threadIdx.x;
  const int s = t & 63;
  const int c0 = __builtin_amdgcn_readfirstlane(t >> 6) * 16;
  const int e = blockIdx.x*EB + s;

  {
    const uint4* zp = (const uint4*)(z + (size_t)e*C + c0);
    const uint4 v0 = zp[0], v1 = zp[1];
    const unsigned int u[8] = {v0.x,v0.y,v0.z,v0.w,v1.x,v1.y,v1.z,v1.w};
#pragma unroll
    for (int q=0;q<8;++q){
      const int cc = c0 + 2*q;
      const float f0 = bfbits(u[q] << 16);
      const float f1 = bfbits(u[q] & 0xffff0000u);
      hbuf[s][cc]   = lrelu(fmaf(coefs2[cc],   f0, coefs2[64+cc]));
      hbuf[s][cc+1] = lrelu(fmaf(coefs2[cc+1], f1, coefs2[64+cc+1]));
    }
  }
  __syncthreads();

  float acc[16];
#pragma unroll
  for (int j=0;j<16;++j) acc[j] = b3[c0+j];
#pragma unroll 8
  for (int k=0;k<C;++k){
    const float hk = hbuf[s][k];
    const float* __restrict__ wp = W3 + (k<<6) + c0;
#pragma unroll
    for (int j=0;j<16;++j) acc[j] = fmaf(hk, wp[j], acc[j]);
  }

  // segment max across the 16 edges of each node (16-lane groups)
#pragma unroll
  for (int j=0;j<16;++j){
    float m = acc[j];
    m = fmaxf(m, __shfl_xor(m, 1, 64));
    m = fmaxf(m, __shfl_xor(m, 2, 64));
    m = fmaxf(m, __shfl_xor(m, 4, 64));
    m = fmaxf(m, __shfl_xor(m, 8, 64));
    acc[j] = m;
  }

  if ((s & 15) == 0){
    const int node = e >> 4;
    const float* __restrict__ xr = x + (size_t)node*C + c0;
    float* __restrict__ op = out + (size_t)node*C + c0;
#pragma unroll
    for (int j=0;j<16;++j) op[j] = lrelu(acc[j] + xr[j]);
  }
}

extern "C" void kernel_launch(void* const* d_in, const int* in_sizes, int n_in,
                              void* d_out, int out_size, void* d_ws, size_t ws_size,
                              hipStream_t stream) {
  const float* x   = (const float*)d_in[0];
  const int*   ei  = (const int*)d_in[1];   // int32 (jax x64 disabled)
  const float* W1  = (const float*)d_in[2];
  const float* b1  = (const float*)d_in[3];
  const float* g1  = (const float*)d_in[4];
  const float* be1 = (const float*)d_in[5];
  const float* W2  = (const float*)d_in[6];
  const float* b2  = (const float*)d_in[7];
  const float* g2  = (const float*)d_in[8];
  const float* be2 = (const float*)d_in[9];
  const float* W3  = (const float*)d_in[10];
  const float* b3  = (const float*)d_in[11];
  float* out = (float*)d_out;

  float* stats = (float*)d_ws;                 // [256]: sum1,sq1,sum2,sq2
  float* coefs = stats + 256;                  // [256]: a1,c1,a2,c2
  unsigned short* z = (unsigned short*)(stats + 512);  // [E*64] bf16, in-place z1/z2

  hipMemsetAsync(stats, 0, 256*sizeof(float), stream);
  kA<<<2560, 256, 0, stream>>>(x, ei, W1, b1, z, stats);
  kFin<<<1, 64, 0, stream>>>(stats, g1, be1, coefs, 0);
  kB<<<2560, 256, 0, stream>>>(z, W2, b2, coefs, stats);
  kFin<<<1, 64, 0, stream>>>(stats, g2, be2, coefs, 1);
  kC<<<NTILE, 256, 0, stream>>>(z, W3, b3, coefs + 128, x, out);
}

// Round 2
// 380.755 us; speedup vs baseline: 5.7267x; 5.7267x over previous
//
#include <hip/hip_runtime.h>
#include <hip/hip_bf16.h>

#define N_NODES 50000
#define KNN     16
#define NEDGE   (N_NODES*KNN)     // 800000
#define NTILE   (NEDGE/64)        // 12500 block-tiles of 64 edges
#define NBLK    1024              // grid for kA/kB (stats partials)
#define SLOPE   0.01f
#define EPS     1e-5f

typedef __attribute__((ext_vector_type(8))) short bf16x8;
typedef __attribute__((ext_vector_type(4))) float f32x4;

__device__ __forceinline__ float bfbits(unsigned int u){ union{unsigned u;float f;}v; v.u=u; return v.f; }
__device__ __forceinline__ unsigned short f2bf(float f){
  union{__hip_bfloat16 h; unsigned short u;}v; v.h=__float2bfloat16(f); return v.u;
}
__device__ __forceinline__ bf16x8 asfrag(uint4 u){ union{uint4 v; bf16x8 b;}q; q.v=u; return q.b; }
__device__ __forceinline__ f32x4 ld4(const float* p){ return *(const f32x4*)p; }
__device__ __forceinline__ f32x4 MFMA(bf16x8 a, bf16x8 b, f32x4 c){
  return __builtin_amdgcn_mfma_f32_16x16x32_bf16(a, b, c, 0, 0, 0);
}

// pack two float4 into a bf16x8 A-fragment
__device__ __forceinline__ bf16x8 pack8(float4 a, float4 b){
  bf16x8 r;
  r[0]=(short)f2bf(a.x); r[1]=(short)f2bf(a.y); r[2]=(short)f2bf(a.z); r[3]=(short)f2bf(a.w);
  r[4]=(short)f2bf(b.x); r[5]=(short)f2bf(b.y); r[6]=(short)f2bf(b.z); r[7]=(short)f2bf(b.w);
  return r;
}
__device__ __forceinline__ bf16x8 pack8d(float4 a, float4 b, float4 ia, float4 ib){
  bf16x8 r;
  r[0]=(short)f2bf(a.x-ia.x); r[1]=(short)f2bf(a.y-ia.y); r[2]=(short)f2bf(a.z-ia.z); r[3]=(short)f2bf(a.w-ia.w);
  r[4]=(short)f2bf(b.x-ib.x); r[5]=(short)f2bf(b.y-ib.y); r[6]=(short)f2bf(b.z-ib.z); r[7]=(short)f2bf(b.w-ib.w);
  return r;
}
// BN(affine)+lrelu on a packed bf16 z-fragment, returns bf16 A-fragment
__device__ __forceinline__ bf16x8 bnact(uint4 u, f32x4 a0, f32x4 a1, f32x4 c0, f32x4 c1){
  union{uint4 v; unsigned short s[8];}q; q.v=u;
  bf16x8 r;
#pragma unroll
  for (int e=0;e<8;++e){
    const float a = (e<4) ? a0[e&3] : a1[e&3];
    const float c = (e<4) ? c0[e&3] : c1[e&3];
    float h = fmaf(a, bfbits((unsigned)q.s[e]<<16), c);
    h = h>=0.f ? h : SLOPE*h;
    r[e] = (short)f2bf(h);
  }
  return r;
}

// ---- kPrep: pack W1/W2/W3 into MFMA B-fragment tables (bf16) -----------
// entry idx -> lane l=idx&63, frag f: B[k=ks*32+(l>>4)*8+e][col=nf*16+(l&15)]
__global__ void kPrep(const float* __restrict__ W1, const float* __restrict__ W2,
                      const float* __restrict__ W3, unsigned short* __restrict__ wf)
{
  for (int idx = threadIdx.x; idx < 2048; idx += blockDim.x){
    const float* W; int fi;
    if (idx < 1024)      { W = W1; fi = idx >> 6; }
    else if (idx < 1536) { W = W2; fi = (idx-1024) >> 6; }
    else                 { W = W3; fi = (idx-1536) >> 6; }
    const int l  = idx & 63;
    const int ks = fi >> 2, nf = fi & 3;
    const int k0 = ks*32 + ((l>>4)<<3);
    const int col = nf*16 + (l&15);
    unsigned short* o = wf + (size_t)idx*8;
#pragma unroll
    for (int e=0;e<8;++e) o[e] = f2bf(W[(size_t)(k0+e)*64 + col]);
  }
}

// ---- kA: gather -> h frags -> z1 = h@W1+b1 (MFMA) -> stats partials ----
__global__ __launch_bounds__(256) void kA(const float* __restrict__ x,
    const int* __restrict__ ei, const uint4* __restrict__ wf,
    const float* __restrict__ b1, unsigned short* __restrict__ z,
    float* __restrict__ part)
{
  __shared__ float red[4][128];
  const int t = threadIdx.x, w = t>>6, l = t&63;
  const int lr = l&15, lg = l>>4;

  bf16x8 wfr[16];
#pragma unroll
  for (int f=0;f<16;++f) wfr[f] = asfrag(wf[f*64 + l]);
  float bb[4];
#pragma unroll
  for (int nf=0;nf<4;++nf) bb[nf] = b1[nf*16 + lr];

  float sumP[4] = {0,0,0,0}, sqP[4] = {0,0,0,0};

  for (int tile = blockIdx.x; tile < NTILE; tile += gridDim.x){
    const int e0   = tile*64 + w*16;          // wave-tile = one node's 16 edges
    const int node = e0 >> 4;
    const int src  = ei[e0 + lr];
    const float* xr = x + (size_t)node*64 + lg*8;
    const float* sr = x + (size_t)src*64  + lg*8;
    const float4 xi0a = ((const float4*)xr)[0],      xi0b = ((const float4*)xr)[1];
    const float4 xi1a = ((const float4*)(xr+32))[0], xi1b = ((const float4*)(xr+32))[1];
    const float4 xj0a = ((const float4*)sr)[0],      xj0b = ((const float4*)sr)[1];
    const float4 xj1a = ((const float4*)(sr+32))[0], xj1b = ((const float4*)(sr+32))[1];

    const bf16x8 a0 = pack8 (xi0a, xi0b);               // h cols 0..31  (x_i)
    const bf16x8 a1 = pack8 (xi1a, xi1b);               // h cols 32..63
    const bf16x8 a2 = pack8d(xj0a, xj0b, xi0a, xi0b);   // h cols 64..95  (x_j - x_i)
    const bf16x8 a3 = pack8d(xj1a, xj1b, xi1a, xi1b);   // h cols 96..127

    f32x4 acc[4];
#pragma unroll
    for (int nf=0;nf<4;++nf) acc[nf] = (f32x4){bb[nf],bb[nf],bb[nf],bb[nf]};
#pragma unroll
    for (int nf=0;nf<4;++nf){
      acc[nf] = MFMA(a0, wfr[0*4+nf], acc[nf]);
      acc[nf] = MFMA(a1, wfr[1*4+nf], acc[nf]);
      acc[nf] = MFMA(a2, wfr[2*4+nf], acc[nf]);
      acc[nf] = MFMA(a3, wfr[3*4+nf], acc[nf]);
    }

    unsigned short* zp = z + (size_t)(e0 + lg*4)*64 + lr;
#pragma unroll
    for (int nf=0;nf<4;++nf){
#pragma unroll
      for (int r=0;r<4;++r){
        const float v = acc[nf][r];
        sumP[nf] += v; sqP[nf] = fmaf(v, v, sqP[nf]);
        zp[(size_t)r*64 + nf*16] = f2bf(v);
      }
    }
  }

#pragma unroll
  for (int nf=0;nf<4;++nf){
    float s = sumP[nf], q = sqP[nf];
    s += __shfl_xor(s,16,64); s += __shfl_xor(s,32,64);
    q += __shfl_xor(q,16,64); q += __shfl_xor(q,32,64);
    if (l < 16){ red[w][nf*16+l] = s; red[w][64+nf*16+l] = q; }
  }
  __syncthreads();
  if (t < 128)
    part[(size_t)blockIdx.x*128 + t] = red[0][t]+red[1][t]+red[2][t]+red[3][t];
}

// ---- kFin: reduce per-block partials -> BN affine coefs ---------------
__global__ void kFin(const float* __restrict__ part, const float* __restrict__ g,
                     const float* __restrict__ be, float* __restrict__ coefs)
{
  __shared__ float red[256];
  const int t = threadIdx.x, c = t & 127, h = t >> 7;
  float a = 0.f;
  for (int b = h; b < NBLK; b += 2) a += part[(size_t)b*128 + c];
  red[t] = a;
  __syncthreads();
  if (t < 128) red[t] = red[t] + red[t+128];
  __syncthreads();
  if (t < 64){
    const float inv  = 1.0f/(float)NEDGE;
    const float mean = red[t]*inv;
    const float var  = red[64+t]*inv - mean*mean;
    const float aa   = g[t]*rsqrtf(var + EPS);
    coefs[t]      = aa;
    coefs[64 + t] = be[t] - mean*aa;
  }
}

// ---- kB: h1=lrelu(bn(z1)); z2=h1@W2+b2 (in-place); stats2 --------------
__global__ __launch_bounds__(256) void kB(unsigned short* __restrict__ z,
    const uint4* __restrict__ wf, const float* __restrict__ b2,
    const float* __restrict__ coefs, float* __restrict__ part)
{
  __shared__ float red[4][128];
  const int t = threadIdx.x, w = t>>6, l = t&63;
  const int lr = l&15, lg = l>>4;

  bf16x8 wfr[8];
#pragma unroll
  for (int f=0;f<8;++f) wfr[f] = asfrag(wf[1024 + f*64 + l]);
  const int kb = lg*8;
  const f32x4 A00 = ld4(coefs + kb),        A01 = ld4(coefs + kb + 4);
  const f32x4 A10 = ld4(coefs + 32 + kb),   A11 = ld4(coefs + 32 + kb + 4);
  const f32x4 C00 = ld4(coefs + 64 + kb),   C01 = ld4(coefs + 64 + kb + 4);
  const f32x4 C10 = ld4(coefs + 96 + kb),   C11 = ld4(coefs + 96 + kb + 4);
  float bb[4];
#pragma unroll
  for (int nf=0;nf<4;++nf) bb[nf] = b2[nf*16 + lr];

  float sumP[4] = {0,0,0,0}, sqP[4] = {0,0,0,0};

  for (int tile = blockIdx.x; tile < NTILE; tile += gridDim.x){
    const int e0 = tile*64 + w*16;
    const unsigned short* zr = z + (size_t)(e0+lr)*64 + kb;
    const uint4 r0 = *(const uint4*)(zr);
    const uint4 r1 = *(const uint4*)(zr + 32);
    const bf16x8 a0 = bnact(r0, A00, A01, C00, C01);
    const bf16x8 a1 = bnact(r1, A10, A11, C10, C11);

    f32x4 acc[4];
#pragma unroll
    for (int nf=0;nf<4;++nf) acc[nf] = (f32x4){bb[nf],bb[nf],bb[nf],bb[nf]};
#pragma unroll
    for (int nf=0;nf<4;++nf){
      acc[nf] = MFMA(a0, wfr[nf],   acc[nf]);
      acc[nf] = MFMA(a1, wfr[4+nf], acc[nf]);
    }

    unsigned short* zp = z + (size_t)(e0 + lg*4)*64 + lr;   // in-place: same rows read
#pragma unroll
    for (int nf=0;nf<4;++nf){
#pragma unroll
      for (int r=0;r<4;++r){
        const float v = acc[nf][r];
        sumP[nf] += v; sqP[nf] = fmaf(v, v, sqP[nf]);
        zp[(size_t)r*64 + nf*16] = f2bf(v);
      }
    }
  }

#pragma unroll
  for (int nf=0;nf<4;++nf){
    float s = sumP[nf], q = sqP[nf];
    s += __shfl_xor(s,16,64); s += __shfl_xor(s,32,64);
    q += __shfl_xor(q,16,64); q += __shfl_xor(q,32,64);
    if (l < 16){ red[w][nf*16+l] = s; red[w][64+nf*16+l] = q; }
  }
  __syncthreads();
  if (t < 128)
    part[(size_t)blockIdx.x*128 + t] = red[0][t]+red[1][t]+red[2][t]+red[3][t];
}

// ---- kC: h2=lrelu(bn(z2)); z3=h2@W3+b3; segmax over node; residual ----
__global__ __launch_bounds__(256) void kC(const unsigned short* __restrict__ z,
    const uint4* __restrict__ wf, const float* __restrict__ b3,
    const float* __restrict__ coefs, const float* __restrict__ x,
    float* __restrict__ out)
{
  const int t = threadIdx.x, w = t>>6, l = t&63;
  const int lr = l&15, lg = l>>4;

  bf16x8 wfr[8];
#pragma unroll
  for (int f=0;f<8;++f) wfr[f] = asfrag(wf[1536 + f*64 + l]);
  const int kb = lg*8;
  const f32x4 A00 = ld4(coefs + kb),        A01 = ld4(coefs + kb + 4);
  const f32x4 A10 = ld4(coefs + 32 + kb),   A11 = ld4(coefs + 32 + kb + 4);
  const f32x4 C00 = ld4(coefs + 64 + kb),   C01 = ld4(coefs + 64 + kb + 4);
  const f32x4 C10 = ld4(coefs + 96 + kb),   C11 = ld4(coefs + 96 + kb + 4);
  float bb[4];
#pragma unroll
  for (int nf=0;nf<4;++nf) bb[nf] = b3[nf*16 + lr];

  for (int tile = blockIdx.x; tile < NTILE; tile += gridDim.x){
    const int e0   = tile*64 + w*16;
    const int node = e0 >> 4;
    const unsigned short* zr = z + (size_t)(e0+lr)*64 + kb;
    const uint4 r0 = *(const uint4*)(zr);
    const uint4 r1 = *(const uint4*)(zr + 32);
    const bf16x8 a0 = bnact(r0, A00, A01, C00, C01);
    const bf16x8 a1 = bnact(r1, A10, A11, C10, C11);

    f32x4 acc[4];
#pragma unroll
    for (int nf=0;nf<4;++nf) acc[nf] = (f32x4){bb[nf],bb[nf],bb[nf],bb[nf]};
#pragma unroll
    for (int nf=0;nf<4;++nf){
      acc[nf] = MFMA(a0, wfr[nf],   acc[nf]);
      acc[nf] = MFMA(a1, wfr[4+nf], acc[nf]);
    }

    // segment-max: wave-tile rows = this node's 16 edges
#pragma unroll
    for (int nf=0;nf<4;++nf){
      float m = fmaxf(fmaxf(acc[nf][0],acc[nf][1]), fmaxf(acc[nf][2],acc[nf][3]));
      m = fmaxf(m, __shfl_xor(m,16,64));
      m = fmaxf(m, __shfl_xor(m,32,64));
      if (l < 16){
        const float xv = x[(size_t)node*64 + nf*16 + l];
        float o = m + xv;
        out[(size_t)node*64 + nf*16 + l] = (o>=0.f ? o : SLOPE*o);
      }
    }
  }
}

extern "C" void kernel_launch(void* const* d_in, const int* in_sizes, int n_in,
                              void* d_out, int out_size, void* d_ws, size_t ws_size,
                              hipStream_t stream) {
  const float* x   = (const float*)d_in[0];
  const int*   ei  = (const int*)d_in[1];
  const float* W1  = (const float*)d_in[2];
  const float* b1  = (const float*)d_in[3];
  const float* g1  = (const float*)d_in[4];
  const float* be1 = (const float*)d_in[5];
  const float* W2  = (const float*)d_in[6];
  const float* b2  = (const float*)d_in[7];
  const float* g2  = (const float*)d_in[8];
  const float* be2 = (const float*)d_in[9];
  const float* W3  = (const float*)d_in[10];
  const float* b3  = (const float*)d_in[11];
  float* out = (float*)d_out;

  // ws layout
  unsigned short* z     = (unsigned short*)d_ws;                         // 102,400,000 B
  float*          coefs = (float*)((char*)d_ws + 102400000);             // 256 f32 (1 KB)
  float*          part1 = (float*)((char*)d_ws + 102401024);             // NBLK*128 f32
  float*          part2 = part1 + (size_t)NBLK*128;                      // NBLK*128 f32
  unsigned short* wfb   = (unsigned short*)((char*)part2 + (size_t)NBLK*128*4); // 32 KB

  kPrep<<<1, 256, 0, stream>>>(W1, W2, W3, wfb);
  kA<<<NBLK, 256, 0, stream>>>(x, ei, (const uint4*)wfb, b1, z, part1);
  kFin<<<1, 256, 0, stream>>>(part1, g1, be1, coefs);
  kB<<<NBLK, 256, 0, stream>>>(z, (const uint4*)wfb, b2, coefs, part2);
  kFin<<<1, 256, 0, stream>>>(part2, g2, be2, coefs + 128);
  kC<<<2048, 256, 0, stream>>>(z, (const uint4*)wfb, b3, coefs + 128, x, out);
}

// Round 3
// 146.224 us; speedup vs baseline: 14.9118x; 2.6039x over previous
//
#include <hip/hip_runtime.h>
#include <hip/hip_bf16.h>

#define N_NODES 50000
#define KNN     16
#define NEDGE   (N_NODES*KNN)     // 800000
#define NTILE   (NEDGE/64)        // 12500 block-tiles of 64 edges
#define NBLK    1024              // grid for kA/kB (stats partials)
#define SLOPE   0.01f
#define EPS     1e-5f

typedef __attribute__((ext_vector_type(8))) short bf16x8;
typedef __attribute__((ext_vector_type(4))) float f32x4;

__device__ __forceinline__ float bfbits(unsigned int u){ union{unsigned u;float f;}v; v.u=u; return v.f; }
__device__ __forceinline__ unsigned short f2bf(float f){
  union{__hip_bfloat16 h; unsigned short u;}v; v.h=__float2bfloat16(f); return v.u;
}
__device__ __forceinline__ bf16x8 asfrag(uint4 u){ union{uint4 v; bf16x8 b;}q; q.v=u; return q.b; }
__device__ __forceinline__ f32x4 ld4(const float* p){ return *(const f32x4*)p; }
__device__ __forceinline__ f32x4 MFMA(bf16x8 a, bf16x8 b, f32x4 c){
  return __builtin_amdgcn_mfma_f32_16x16x32_bf16(a, b, c, 0, 0, 0);
}

// pack two float4 into a bf16x8 A-fragment
__device__ __forceinline__ bf16x8 pack8(float4 a, float4 b){
  bf16x8 r;
  r[0]=(short)f2bf(a.x); r[1]=(short)f2bf(a.y); r[2]=(short)f2bf(a.z); r[3]=(short)f2bf(a.w);
  r[4]=(short)f2bf(b.x); r[5]=(short)f2bf(b.y); r[6]=(short)f2bf(b.z); r[7]=(short)f2bf(b.w);
  return r;
}
__device__ __forceinline__ bf16x8 pack8d(float4 a, float4 b, float4 ia, float4 ib){
  bf16x8 r;
  r[0]=(short)f2bf(a.x-ia.x); r[1]=(short)f2bf(a.y-ia.y); r[2]=(short)f2bf(a.z-ia.z); r[3]=(short)f2bf(a.w-ia.w);
  r[4]=(short)f2bf(b.x-ib.x); r[5]=(short)f2bf(b.y-ib.y); r[6]=(short)f2bf(b.z-ib.z); r[7]=(short)f2bf(b.w-ib.w);
  return r;
}
// BN(affine)+lrelu on a packed bf16 z-fragment, returns bf16 A-fragment
__device__ __forceinline__ bf16x8 bnact(uint4 u, f32x4 a0, f32x4 a1, f32x4 c0, f32x4 c1){
  union{uint4 v; unsigned short s[8];}q; q.v=u;
  bf16x8 r;
#pragma unroll
  for (int e=0;e<8;++e){
    const float a = (e<4) ? a0[e&3] : a1[e&3];
    const float c = (e<4) ? c0[e&3] : c1[e&3];
    float h = fmaf(a, bfbits((unsigned)q.s[e]<<16), c);
    h = h>=0.f ? h : SLOPE*h;
    r[e] = (short)f2bf(h);
  }
  return r;
}

// ---- kPrep: pack W1/W2/W3 into MFMA B-fragment tables (bf16) -----------
// entry idx -> lane l=idx&63, frag f: B[k=ks*32+(l>>4)*8+e][col=nf*16+(l&15)]
__global__ __launch_bounds__(256) void kPrep(const float* __restrict__ W1,
                      const float* __restrict__ W2,
                      const float* __restrict__ W3, unsigned short* __restrict__ wf)
{
  const int idx = blockIdx.x*256 + threadIdx.x;   // 8 blocks x 256 = 2048 entries
  const float* W; int fi;
  if (idx < 1024)      { W = W1; fi = idx >> 6; }
  else if (idx < 1536) { W = W2; fi = (idx-1024) >> 6; }
  else                 { W = W3; fi = (idx-1536) >> 6; }
  const int l  = idx & 63;
  const int ks = fi >> 2, nf = fi & 3;
  const int k0 = ks*32 + ((l>>4)<<3);
  const int col = nf*16 + (l&15);
  unsigned short* o = wf + (size_t)idx*8;
#pragma unroll
  for (int e=0;e<8;++e) o[e] = f2bf(W[(size_t)(k0+e)*64 + col]);
}

// ---- kA: gather -> h frags -> z1 = h@W1+b1 (MFMA) -> stats partials ----
__global__ __launch_bounds__(256) void kA(const float* __restrict__ x,
    const int* __restrict__ ei, const uint4* __restrict__ wf,
    const float* __restrict__ b1, unsigned short* __restrict__ z,
    float* __restrict__ part)
{
  __shared__ float red[4][128];
  const int t = threadIdx.x, w = t>>6, l = t&63;
  const int lr = l&15, lg = l>>4;

  bf16x8 wfr[16];
#pragma unroll
  for (int f=0;f<16;++f) wfr[f] = asfrag(wf[f*64 + l]);
  float bb[4];
#pragma unroll
  for (int nf=0;nf<4;++nf) bb[nf] = b1[nf*16 + lr];

  float sumP[4] = {0,0,0,0}, sqP[4] = {0,0,0,0};

  for (int tile = blockIdx.x; tile < NTILE; tile += gridDim.x){
    const int e0   = tile*64 + w*16;          // wave-tile = one node's 16 edges
    const int node = e0 >> 4;
    const int src  = ei[e0 + lr];
    const float* xr = x + (size_t)node*64 + lg*8;
    const float* sr = x + (size_t)src*64  + lg*8;
    const float4 xi0a = ((const float4*)xr)[0],      xi0b = ((const float4*)xr)[1];
    const float4 xi1a = ((const float4*)(xr+32))[0], xi1b = ((const float4*)(xr+32))[1];
    const float4 xj0a = ((const float4*)sr)[0],      xj0b = ((const float4*)sr)[1];
    const float4 xj1a = ((const float4*)(sr+32))[0], xj1b = ((const float4*)(sr+32))[1];

    const bf16x8 a0 = pack8 (xi0a, xi0b);               // h cols 0..31  (x_i)
    const bf16x8 a1 = pack8 (xi1a, xi1b);               // h cols 32..63
    const bf16x8 a2 = pack8d(xj0a, xj0b, xi0a, xi0b);   // h cols 64..95  (x_j - x_i)
    const bf16x8 a3 = pack8d(xj1a, xj1b, xi1a, xi1b);   // h cols 96..127

    f32x4 acc[4];
#pragma unroll
    for (int nf=0;nf<4;++nf) acc[nf] = (f32x4){bb[nf],bb[nf],bb[nf],bb[nf]};
#pragma unroll
    for (int nf=0;nf<4;++nf){
      acc[nf] = MFMA(a0, wfr[0*4+nf], acc[nf]);
      acc[nf] = MFMA(a1, wfr[1*4+nf], acc[nf]);
      acc[nf] = MFMA(a2, wfr[2*4+nf], acc[nf]);
      acc[nf] = MFMA(a3, wfr[3*4+nf], acc[nf]);
    }

    unsigned short* zp = z + (size_t)(e0 + lg*4)*64 + lr;
#pragma unroll
    for (int nf=0;nf<4;++nf){
#pragma unroll
      for (int r=0;r<4;++r){
        const float v = acc[nf][r];
        sumP[nf] += v; sqP[nf] = fmaf(v, v, sqP[nf]);
        zp[(size_t)r*64 + nf*16] = f2bf(v);
      }
    }
  }

#pragma unroll
  for (int nf=0;nf<4;++nf){
    float s = sumP[nf], q = sqP[nf];
    s += __shfl_xor(s,16,64); s += __shfl_xor(s,32,64);
    q += __shfl_xor(q,16,64); q += __shfl_xor(q,32,64);
    if (l < 16){ red[w][nf*16+l] = s; red[w][64+nf*16+l] = q; }
  }
  __syncthreads();
  if (t < 128)   // transposed: part[stat*NBLK + block] -> coalesced kFin reads
    part[(size_t)t*NBLK + blockIdx.x] = red[0][t]+red[1][t]+red[2][t]+red[3][t];
}

// ---- kFin: 64 blocks, block c reduces sum-row c and sq-row 64+c --------
__global__ __launch_bounds__(256) void kFin(const float* __restrict__ part,
    const float* __restrict__ g, const float* __restrict__ be,
    float* __restrict__ coefs)
{
  __shared__ float rs[256], rq[256];
  const int c = blockIdx.x;      // channel 0..63
  const int t = threadIdx.x;
  const float* ps = part + (size_t)c*NBLK;
  const float* pq = part + (size_t)(64+c)*NBLK;
  float s = 0.f, q = 0.f;
#pragma unroll
  for (int i=0;i<NBLK/256;++i){ s += ps[t + i*256]; q += pq[t + i*256]; }
  rs[t]=s; rq[t]=q;
  __syncthreads();
#pragma unroll
  for (int off=128; off>0; off>>=1){
    if (t < off){ rs[t]+=rs[t+off]; rq[t]+=rq[t+off]; }
    __syncthreads();
  }
  if (t==0){
    const float inv  = 1.0f/(float)NEDGE;
    const float mean = rs[0]*inv;
    const float var  = rq[0]*inv - mean*mean;
    const float a    = g[c]*rsqrtf(var + EPS);
    coefs[c]      = a;
    coefs[64 + c] = be[c] - mean*a;
  }
}

// ---- kB: h1=lrelu(bn(z1)); z2=h1@W2+b2 (in-place); stats2 --------------
__global__ __launch_bounds__(256) void kB(unsigned short* __restrict__ z,
    const uint4* __restrict__ wf, const float* __restrict__ b2,
    const float* __restrict__ coefs, float* __restrict__ part)
{
  __shared__ float red[4][128];
  const int t = threadIdx.x, w = t>>6, l = t&63;
  const int lr = l&15, lg = l>>4;

  bf16x8 wfr[8];
#pragma unroll
  for (int f=0;f<8;++f) wfr[f] = asfrag(wf[1024 + f*64 + l]);
  const int kb = lg*8;
  const f32x4 A00 = ld4(coefs + kb),        A01 = ld4(coefs + kb + 4);
  const f32x4 A10 = ld4(coefs + 32 + kb),   A11 = ld4(coefs + 32 + kb + 4);
  const f32x4 C00 = ld4(coefs + 64 + kb),   C01 = ld4(coefs + 64 + kb + 4);
  const f32x4 C10 = ld4(coefs + 96 + kb),   C11 = ld4(coefs + 96 + kb + 4);
  float bb[4];
#pragma unroll
  for (int nf=0;nf<4;++nf) bb[nf] = b2[nf*16 + lr];

  float sumP[4] = {0,0,0,0}, sqP[4] = {0,0,0,0};

  for (int tile = blockIdx.x; tile < NTILE; tile += gridDim.x){
    const int e0 = tile*64 + w*16;
    const unsigned short* zr = z + (size_t)(e0+lr)*64 + kb;
    const uint4 r0 = *(const uint4*)(zr);
    const uint4 r1 = *(const uint4*)(zr + 32);
    const bf16x8 a0 = bnact(r0, A00, A01, C00, C01);
    const bf16x8 a1 = bnact(r1, A10, A11, C10, C11);

    f32x4 acc[4];
#pragma unroll
    for (int nf=0;nf<4;++nf) acc[nf] = (f32x4){bb[nf],bb[nf],bb[nf],bb[nf]};
#pragma unroll
    for (int nf=0;nf<4;++nf){
      acc[nf] = MFMA(a0, wfr[nf],   acc[nf]);
      acc[nf] = MFMA(a1, wfr[4+nf], acc[nf]);
    }

    unsigned short* zp = z + (size_t)(e0 + lg*4)*64 + lr;   // in-place: same rows read
#pragma unroll
    for (int nf=0;nf<4;++nf){
#pragma unroll
      for (int r=0;r<4;++r){
        const float v = acc[nf][r];
        sumP[nf] += v; sqP[nf] = fmaf(v, v, sqP[nf]);
        zp[(size_t)r*64 + nf*16] = f2bf(v);
      }
    }
  }

#pragma unroll
  for (int nf=0;nf<4;++nf){
    float s = sumP[nf], q = sqP[nf];
    s += __shfl_xor(s,16,64); s += __shfl_xor(s,32,64);
    q += __shfl_xor(q,16,64); q += __shfl_xor(q,32,64);
    if (l < 16){ red[w][nf*16+l] = s; red[w][64+nf*16+l] = q; }
  }
  __syncthreads();
  if (t < 128)
    part[(size_t)t*NBLK + blockIdx.x] = red[0][t]+red[1][t]+red[2][t]+red[3][t];
}

// ---- kC: h2=lrelu(bn(z2)); z3=h2@W3+b3; segmax over node; residual ----
__global__ __launch_bounds__(256) void kC(const unsigned short* __restrict__ z,
    const uint4* __restrict__ wf, const float* __restrict__ b3,
    const float* __restrict__ coefs, const float* __restrict__ x,
    float* __restrict__ out)
{
  const int t = threadIdx.x, w = t>>6, l = t&63;
  const int lr = l&15, lg = l>>4;

  bf16x8 wfr[8];
#pragma unroll
  for (int f=0;f<8;++f) wfr[f] = asfrag(wf[1536 + f*64 + l]);
  const int kb = lg*8;
  const f32x4 A00 = ld4(coefs + kb),        A01 = ld4(coefs + kb + 4);
  const f32x4 A10 = ld4(coefs + 32 + kb),   A11 = ld4(coefs + 32 + kb + 4);
  const f32x4 C00 = ld4(coefs + 64 + kb),   C01 = ld4(coefs + 64 + kb + 4);
  const f32x4 C10 = ld4(coefs + 96 + kb),   C11 = ld4(coefs + 96 + kb + 4);
  float bb[4];
#pragma unroll
  for (int nf=0;nf<4;++nf) bb[nf] = b3[nf*16 + lr];

  for (int tile = blockIdx.x; tile < NTILE; tile += gridDim.x){
    const int e0   = tile*64 + w*16;
    const int node = e0 >> 4;
    const unsigned short* zr = z + (size_t)(e0+lr)*64 + kb;
    const uint4 r0 = *(const uint4*)(zr);
    const uint4 r1 = *(const uint4*)(zr + 32);
    const bf16x8 a0 = bnact(r0, A00, A01, C00, C01);
    const bf16x8 a1 = bnact(r1, A10, A11, C10, C11);

    f32x4 acc[4];
#pragma unroll
    for (int nf=0;nf<4;++nf) acc[nf] = (f32x4){bb[nf],bb[nf],bb[nf],bb[nf]};
#pragma unroll
    for (int nf=0;nf<4;++nf){
      acc[nf] = MFMA(a0, wfr[nf],   acc[nf]);
      acc[nf] = MFMA(a1, wfr[4+nf], acc[nf]);
    }

    // segment-max: wave-tile rows = this node's 16 edges
#pragma unroll
    for (int nf=0;nf<4;++nf){
      float m = fmaxf(fmaxf(acc[nf][0],acc[nf][1]), fmaxf(acc[nf][2],acc[nf][3]));
      m = fmaxf(m, __shfl_xor(m,16,64));
      m = fmaxf(m, __shfl_xor(m,32,64));
      if (l < 16){
        const float xv = x[(size_t)node*64 + nf*16 + l];
        float o = m + xv;
        out[(size_t)node*64 + nf*16 + l] = (o>=0.f ? o : SLOPE*o);
      }
    }
  }
}

extern "C" void kernel_launch(void* const* d_in, const int* in_sizes, int n_in,
                              void* d_out, int out_size, void* d_ws, size_t ws_size,
                              hipStream_t stream) {
  const float* x   = (const float*)d_in[0];
  const int*   ei  = (const int*)d_in[1];
  const float* W1  = (const float*)d_in[2];
  const float* b1  = (const float*)d_in[3];
  const float* g1  = (const float*)d_in[4];
  const float* be1 = (const float*)d_in[5];
  const float* W2  = (const float*)d_in[6];
  const float* b2  = (const float*)d_in[7];
  const float* g2  = (const float*)d_in[8];
  const float* be2 = (const float*)d_in[9];
  const float* W3  = (const float*)d_in[10];
  const float* b3  = (const float*)d_in[11];
  float* out = (float*)d_out;

  // ws layout
  unsigned short* z     = (unsigned short*)d_ws;                         // 102,400,000 B
  float*          coefs = (float*)((char*)d_ws + 102400000);             // 256 f32 (1 KB)
  float*          part1 = (float*)((char*)d_ws + 102401024);             // 128*NBLK f32 (transposed)
  float*          part2 = part1 + (size_t)NBLK*128;                      // 128*NBLK f32
  unsigned short* wfb   = (unsigned short*)((char*)part2 + (size_t)NBLK*128*4); // 32 KB

  kPrep<<<8, 256, 0, stream>>>(W1, W2, W3, wfb);
  kA<<<NBLK, 256, 0, stream>>>(x, ei, (const uint4*)wfb, b1, z, part1);
  kFin<<<64, 256, 0, stream>>>(part1, g1, be1, coefs);
  kB<<<NBLK, 256, 0, stream>>>(z, (const uint4*)wfb, b2, coefs, part2);
  kFin<<<64, 256, 0, stream>>>(part2, g2, be2, coefs + 128);
  kC<<<2048, 256, 0, stream>>>(z, (const uint4*)wfb, b3, coefs + 128, x, out);
}

// Round 5
// 133.419 us; speedup vs baseline: 16.3430x; 1.0960x over previous
//
#include <hip/hip_runtime.h>
#include <hip/hip_bf16.h>

#define N_NODES 50000
#define KNN     16
#define NEDGE   (N_NODES*KNN)     // 800000
#define NTILE   (NEDGE/64)        // 12500 block-tiles of 64 edges (4 nodes each)
#define NBLK    1024              // grid for kA/kB (stats partials)
#define SLOPE   0.01f
#define EPS     1e-5f

typedef __attribute__((ext_vector_type(8))) short bf16x8;
typedef __attribute__((ext_vector_type(4))) float f32x4;

__device__ __forceinline__ float bfbits(unsigned int u){ union{unsigned u;float f;}v; v.u=u; return v.f; }
__device__ __forceinline__ unsigned short f2bf(float f){
  union{__hip_bfloat16 h; unsigned short u;}v; v.h=__float2bfloat16(f); return v.u;
}
__device__ __forceinline__ bf16x8 asfrag(uint4 u){ union{uint4 v; bf16x8 b;}q; q.v=u; return q.b; }
__device__ __forceinline__ f32x4 ld4(const float* p){ return *(const f32x4*)p; }
__device__ __forceinline__ f32x4 MFMA(bf16x8 a, bf16x8 b, f32x4 c){
  return __builtin_amdgcn_mfma_f32_16x16x32_bf16(a, b, c, 0, 0, 0);
}

__device__ __forceinline__ bf16x8 pack8(float4 a, float4 b){
  bf16x8 r;
  r[0]=(short)f2bf(a.x); r[1]=(short)f2bf(a.y); r[2]=(short)f2bf(a.z); r[3]=(short)f2bf(a.w);
  r[4]=(short)f2bf(b.x); r[5]=(short)f2bf(b.y); r[6]=(short)f2bf(b.z); r[7]=(short)f2bf(b.w);
  return r;
}
// BN(affine)+lrelu on a packed bf16 z-fragment, returns bf16 A-fragment
__device__ __forceinline__ bf16x8 bnact(uint4 u, f32x4 a0, f32x4 a1, f32x4 c0, f32x4 c1){
  union{uint4 v; unsigned short s[8];}q; q.v=u;
  bf16x8 r;
#pragma unroll
  for (int e=0;e<8;++e){
    const float a = (e<4) ? a0[e&3] : a1[e&3];
    const float c = (e<4) ? c0[e&3] : c1[e&3];
    float h = fmaf(a, bfbits((unsigned)q.s[e]<<16), c);
    h = h>=0.f ? h : SLOPE*h;
    r[e] = (short)f2bf(h);
  }
  return r;
}

// ---- kInit: blocks 0..7 pack W fragments (W1 concat-folded); 8..263 cvt x --
// W-frag entry idx -> lane l=idx&63, frag f: B[k=ks*32+(l>>4)*8+e][col=nf*16+(l&15)]
// W1' fold: rows 0..63 become A-B (x_i coefficient), rows 64..127 stay B.
__global__ __launch_bounds__(256) void kInit(const float* __restrict__ W1,
    const float* __restrict__ W2, const float* __restrict__ W3,
    const float* __restrict__ x,
    unsigned short* __restrict__ wf, unsigned short* __restrict__ xb, int doCvt)
{
  if (blockIdx.x < 8){
    const int idx = blockIdx.x*256 + threadIdx.x;   // 2048 entries
    const float* W; int fi; bool fold = false;
    if (idx < 1024)      { W = W1; fi = idx >> 6; fold = (idx < 512); }
    else if (idx < 1536) { W = W2; fi = (idx-1024) >> 6; }
    else                 { W = W3; fi = (idx-1536) >> 6; }
    const int l  = idx & 63;
    const int ks = fi >> 2, nf = fi & 3;
    const int k0 = ks*32 + ((l>>4)<<3);
    const int col = nf*16 + (l&15);
    unsigned short* o = wf + (size_t)idx*8;
#pragma unroll
    for (int e=0;e<8;++e){
      float v = W[(size_t)(k0+e)*64 + col];
      if (fold) v -= W[(size_t)(k0+e+64)*64 + col];
      o[e] = f2bf(v);
    }
  } else if (doCvt){
    const int tid = (blockIdx.x-8)*256 + threadIdx.x;   // 65536 threads
    for (int i = tid; i < (N_NODES*64)/4; i += 65536){
      const float4 v = ((const float4*)x)[i];
      ushort4 o;
      o.x = f2bf(v.x); o.y = f2bf(v.y); o.z = f2bf(v.z); o.w = f2bf(v.w);
      ((ushort4*)xb)[i] = o;
    }
  }
}

// ---- kA: gather -> z1 = [x_i, x_j]@W1' + b1 (MFMA) -> stats partials ------
template<int XB>
__global__ __launch_bounds__(256) void kA(const float* __restrict__ x,
    const unsigned short* __restrict__ xb,
    const int* __restrict__ ei, const uint4* __restrict__ wf,
    const float* __restrict__ b1, unsigned short* __restrict__ z,
    float* __restrict__ part)
{
  __shared__ float red[4][128];
  const int t = threadIdx.x, w = t>>6, l = t&63;
  const int lr = l&15, lg = l>>4;

  bf16x8 wfr[16];
#pragma unroll
  for (int f=0;f<16;++f) wfr[f] = asfrag(wf[f*64 + l]);
  float bb[4];
#pragma unroll
  for (int nf=0;nf<4;++nf) bb[nf] = b1[nf*16 + lr];

  float sumP[4] = {0,0,0,0}, sqP[4] = {0,0,0,0};

  for (int tile = blockIdx.x; tile < NTILE; tile += gridDim.x){
    const int e0   = tile*64 + w*16;          // wave-tile = one node's 16 edges
    const int node = e0 >> 4;
    const int src  = ei[e0 + lr];

    bf16x8 a0, a1, a2, a3;
    if (XB){
      const unsigned short* xiP = xb + (size_t)node*64 + lg*8;
      const unsigned short* xjP = xb + (size_t)src*64  + lg*8;
      a0 = *(const bf16x8*)(xiP);        // x_i ch lg*8..+7   (k 0..31)
      a1 = *(const bf16x8*)(xiP + 32);   // x_i ch 32+lg*8..  (k 32..63)
      a2 = *(const bf16x8*)(xjP);        // x_j ch lg*8..+7   (k 64..95)
      a3 = *(const bf16x8*)(xjP + 32);   // x_j ch 32+lg*8..  (k 96..127)
    } else {
      const float* xr = x + (size_t)node*64 + lg*8;
      const float* sr = x + (size_t)src*64  + lg*8;
      a0 = pack8(((const float4*)xr)[0],      ((const float4*)xr)[1]);
      a1 = pack8(((const float4*)(xr+32))[0], ((const float4*)(xr+32))[1]);
      a2 = pack8(((const float4*)sr)[0],      ((const float4*)sr)[1]);
      a3 = pack8(((const float4*)(sr+32))[0], ((const float4*)(sr+32))[1]);
    }

    f32x4 acc[4];
#pragma unroll
    for (int nf=0;nf<4;++nf) acc[nf] = (f32x4){bb[nf],bb[nf],bb[nf],bb[nf]};
#pragma unroll
    for (int nf=0;nf<4;++nf){
      acc[nf] = MFMA(a0, wfr[0*4+nf], acc[nf]);
      acc[nf] = MFMA(a1, wfr[1*4+nf], acc[nf]);
      acc[nf] = MFMA(a2, wfr[2*4+nf], acc[nf]);
      acc[nf] = MFMA(a3, wfr[3*4+nf], acc[nf]);
    }

    unsigned short* zp = z + (size_t)(e0 + lg*4)*64 + lr;
#pragma unroll
    for (int nf=0;nf<4;++nf){
#pragma unroll
      for (int r=0;r<4;++r){
        const float v = acc[nf][r];
        sumP[nf] += v; sqP[nf] = fmaf(v, v, sqP[nf]);
        zp[(size_t)r*64 + nf*16] = f2bf(v);
      }
    }
  }

#pragma unroll
  for (int nf=0;nf<4;++nf){
    float s = sumP[nf], q = sqP[nf];
    s += __shfl_xor(s,16,64); s += __shfl_xor(s,32,64);
    q += __shfl_xor(q,16,64); q += __shfl_xor(q,32,64);
    if (l < 16){ red[w][nf*16+l] = s; red[w][64+nf*16+l] = q; }
  }
  __syncthreads();
  if (t < 128)   // transposed: part[stat*NBLK + block] -> coalesced kFin reads
    part[(size_t)t*NBLK + blockIdx.x] = red[0][t]+red[1][t]+red[2][t]+red[3][t];
}

// ---- kFin: 64 blocks, block c reduces sum-row c and sq-row 64+c -----------
__global__ __launch_bounds__(256) void kFin(const float* __restrict__ part,
    const float* __restrict__ g, const float* __restrict__ be,
    float* __restrict__ coefs)
{
  __shared__ float rs[256], rq[256];
  const int c = blockIdx.x;      // channel 0..63
  const int t = threadIdx.x;
  const float* ps = part + (size_t)c*NBLK;
  const float* pq = part + (size_t)(64+c)*NBLK;
  float s = 0.f, q = 0.f;
#pragma unroll
  for (int i=0;i<NBLK/256;++i){ s += ps[t + i*256]; q += pq[t + i*256]; }
  rs[t]=s; rq[t]=q;
  __syncthreads();
#pragma unroll
  for (int off=128; off>0; off>>=1){
    if (t < off){ rs[t]+=rs[t+off]; rq[t]+=rq[t+off]; }
    __syncthreads();
  }
  if (t==0){
    const float inv  = 1.0f/(float)NEDGE;
    const float mean = rs[0]*inv;
    const float var  = rq[0]*inv - mean*mean;
    const float a    = g[c]*rsqrtf(var + EPS);
    coefs[c]      = a;
    coefs[64 + c] = be[c] - mean*a;
  }
}

// ---- kB: h1=lrelu(bn(z1)); z2=h1@W2+b2 (in-place); stats2 -----------------
__global__ __launch_bounds__(256) void kB(unsigned short* __restrict__ z,
    const uint4* __restrict__ wf, const float* __restrict__ b2,
    const float* __restrict__ coefs, float* __restrict__ part)
{
  __shared__ float red[4][128];
  const int t = threadIdx.x, w = t>>6, l = t&63;
  const int lr = l&15, lg = l>>4;

  bf16x8 wfr[8];
#pragma unroll
  for (int f=0;f<8;++f) wfr[f] = asfrag(wf[1024 + f*64 + l]);
  const int kb = lg*8;
  const f32x4 A00 = ld4(coefs + kb),        A01 = ld4(coefs + kb + 4);
  const f32x4 A10 = ld4(coefs + 32 + kb),   A11 = ld4(coefs + 32 + kb + 4);
  const f32x4 C00 = ld4(coefs + 64 + kb),   C01 = ld4(coefs + 64 + kb + 4);
  const f32x4 C10 = ld4(coefs + 96 + kb),   C11 = ld4(coefs + 96 + kb + 4);
  float bb[4];
#pragma unroll
  for (int nf=0;nf<4;++nf) bb[nf] = b2[nf*16 + lr];

  float sumP[4] = {0,0,0,0}, sqP[4] = {0,0,0,0};

  for (int tile = blockIdx.x; tile < NTILE; tile += gridDim.x){
    const int e0 = tile*64 + w*16;
    const unsigned short* zr = z + (size_t)(e0+lr)*64 + kb;
    const uint4 r0 = *(const uint4*)(zr);
    const uint4 r1 = *(const uint4*)(zr + 32);
    const bf16x8 a0 = bnact(r0, A00, A01, C00, C01);
    const bf16x8 a1 = bnact(r1, A10, A11, C10, C11);

    f32x4 acc[4];
#pragma unroll
    for (int nf=0;nf<4;++nf) acc[nf] = (f32x4){bb[nf],bb[nf],bb[nf],bb[nf]};
#pragma unroll
    for (int nf=0;nf<4;++nf){
      acc[nf] = MFMA(a0, wfr[nf],   acc[nf]);
      acc[nf] = MFMA(a1, wfr[4+nf], acc[nf]);
    }

    unsigned short* zp = z + (size_t)(e0 + lg*4)*64 + lr;   // in-place: same rows read
#pragma unroll
    for (int nf=0;nf<4;++nf){
#pragma unroll
      for (int r=0;r<4;++r){
        const float v = acc[nf][r];
        sumP[nf] += v; sqP[nf] = fmaf(v, v, sqP[nf]);
        zp[(size_t)r*64 + nf*16] = f2bf(v);
      }
    }
  }

#pragma unroll
  for (int nf=0;nf<4;++nf){
    float s = sumP[nf], q = sqP[nf];
    s += __shfl_xor(s,16,64); s += __shfl_xor(s,32,64);
    q += __shfl_xor(q,16,64); q += __shfl_xor(q,32,64);
    if (l < 16){ red[w][nf*16+l] = s; red[w][64+nf*16+l] = q; }
  }
  __syncthreads();
  if (t < 128)
    part[(size_t)t*NBLK + blockIdx.x] = red[0][t]+red[1][t]+red[2][t]+red[3][t];
}

// ---- kC: h2=lrelu(bn(z2)); z3=h2@W3+b3; segmax over node; residual --------
__global__ __launch_bounds__(256) void kC(const unsigned short* __restrict__ z,
    const uint4* __restrict__ wf, const float* __restrict__ b3,
    const float* __restrict__ coefs, const float* __restrict__ x,
    float* __restrict__ out)
{
  const int t = threadIdx.x, w = t>>6, l = t&63;
  const int lr = l&15, lg = l>>4;

  bf16x8 wfr[8];
#pragma unroll
  for (int f=0;f<8;++f) wfr[f] = asfrag(wf[1536 + f*64 + l]);
  const int kb = lg*8;
  const f32x4 A00 = ld4(coefs + kb),        A01 = ld4(coefs + kb + 4);
  const f32x4 A10 = ld4(coefs + 32 + kb),   A11 = ld4(coefs + 32 + kb + 4);
  const f32x4 C00 = ld4(coefs + 64 + kb),   C01 = ld4(coefs + 64 + kb + 4);
  const f32x4 C10 = ld4(coefs + 96 + kb),   C11 = ld4(coefs + 96 + kb + 4);
  float bb[4];
#pragma unroll
  for (int nf=0;nf<4;++nf) bb[nf] = b3[nf*16 + lr];

  for (int tile = blockIdx.x; tile < NTILE; tile += gridDim.x){
    const int e0   = tile*64 + w*16;
    const int node = e0 >> 4;
    const unsigned short* zr = z + (size_t)(e0+lr)*64 + kb;
    const uint4 r0 = *(const uint4*)(zr);
    const uint4 r1 = *(const uint4*)(zr + 32);
    const bf16x8 a0 = bnact(r0, A00, A01, C00, C01);
    const bf16x8 a1 = bnact(r1, A10, A11, C10, C11);

    f32x4 acc[4];
#pragma unroll
    for (int nf=0;nf<4;++nf) acc[nf] = (f32x4){bb[nf],bb[nf],bb[nf],bb[nf]};
#pragma unroll
    for (int nf=0;nf<4;++nf){
      acc[nf] = MFMA(a0, wfr[nf],   acc[nf]);
      acc[nf] = MFMA(a1, wfr[4+nf], acc[nf]);
    }

    // segment-max: wave-tile rows = this node's 16 edges
#pragma unroll
    for (int nf=0;nf<4;++nf){
      float m = fmaxf(fmaxf(acc[nf][0],acc[nf][1]), fmaxf(acc[nf][2],acc[nf][3]));
      m = fmaxf(m, __shfl_xor(m,16,64));
      m = fmaxf(m, __shfl_xor(m,32,64));
      if (l < 16){
        const float xv = x[(size_t)node*64 + nf*16 + l];
        float o = m + xv;
        out[(size_t)node*64 + nf*16 + l] = (o>=0.f ? o : SLOPE*o);
      }
    }
  }
}

extern "C" void kernel_launch(void* const* d_in, const int* in_sizes, int n_in,
                              void* d_out, int out_size, void* d_ws, size_t ws_size,
                              hipStream_t stream) {
  const float* x   = (const float*)d_in[0];
  const int*   ei  = (const int*)d_in[1];
  const float* W1  = (const float*)d_in[2];
  const float* b1  = (const float*)d_in[3];
  const float* g1  = (const float*)d_in[4];
  const float* be1 = (const float*)d_in[5];
  const float* W2  = (const float*)d_in[6];
  const float* b2  = (const float*)d_in[7];
  const float* g2  = (const float*)d_in[8];
  const float* be2 = (const float*)d_in[9];
  const float* W3  = (const float*)d_in[10];
  const float* b3  = (const float*)d_in[11];
  float* out = (float*)d_out;

  // ws layout
  const size_t ZB = 102400000;                       // z: E*64 bf16
  unsigned short* z     = (unsigned short*)d_ws;
  float*          coefs = (float*)((char*)d_ws + ZB);                   // 1 KB
  float*          part1 = (float*)((char*)d_ws + ZB + 1024);            // 512 KB
  float*          part2 = part1 + (size_t)NBLK*128;                     // 512 KB
  unsigned short* wfb   = (unsigned short*)((char*)part2 + (size_t)NBLK*128*4); // 32 KB
  unsigned short* xb    = (unsigned short*)((char*)wfb + 32768);        // 6.4 MB
  const size_t need = ZB + 1024 + 2*(size_t)NBLK*128*4 + 32768 + (size_t)N_NODES*64*2;
  const int useXb = (ws_size >= need) ? 1 : 0;

  kInit<<<useXb ? 264 : 8, 256, 0, stream>>>(W1, W2, W3, x, wfb, xb, useXb);
  if (useXb)
    kA<1><<<NBLK, 256, 0, stream>>>(x, xb, ei, (const uint4*)wfb, b1, z, part1);
  else
    kA<0><<<NBLK, 256, 0, stream>>>(x, xb, ei, (const uint4*)wfb, b1, z, part1);
  kFin<<<64, 256, 0, stream>>>(part1, g1, be1, coefs);
  kB<<<NBLK, 256, 0, stream>>>(z, (const uint4*)wfb, b2, coefs, part2);
  kFin<<<64, 256, 0, stream>>>(part2, g2, be2, coefs + 128);
  kC<<<2048, 256, 0, stream>>>(z, (const uint4*)wfb, b3, coefs + 128, x, out);
}